// Round 7
// baseline (545.257 us; speedup 1.0000x reference)
//
#include <hip/hip_runtime.h>
#include <math.h>

#define B_ 4
#define N_ 20000
#define E_ 100000
#define C_ 128
#define K_ 32
#define NPAD 20480   // padded node count (multiple of 64)
#define NROWS (B_*N_ + 128)   // row slack so unguarded tile reads stay in-bounds

typedef __attribute__((ext_vector_type(8))) short short8;
typedef __attribute__((ext_vector_type(4))) float floatx4;
typedef __attribute__((ext_vector_type(4))) unsigned int uintx4;
typedef __attribute__((ext_vector_type(2))) unsigned int uintx2;

__device__ __forceinline__ float gelu_exact(float x){
    return 0.5f * x * (1.0f + erff(x * 0.70710678118654752f));
}

__device__ __forceinline__ unsigned short f2bf(float f){
    unsigned int u = __builtin_bit_cast(unsigned int, f);
    u += 0x7FFFu + ((u >> 16) & 1u);   // RNE
    return (unsigned short)(u >> 16);
}
__device__ __forceinline__ unsigned int pack2(float a, float b){
    return (unsigned int)f2bf(a) | ((unsigned int)f2bf(b) << 16);
}
__device__ __forceinline__ float bf2f(unsigned short u){
    unsigned int v = ((unsigned int)u) << 16;
    return __builtin_bit_cast(float, v);
}
__device__ __forceinline__ float u2f(unsigned int u){
    return __builtin_bit_cast(float, u);
}

#define WAITV(n) asm volatile("s_waitcnt vmcnt(" #n ")" ::: "memory")
#define BAR() __builtin_amdgcn_s_barrier()

// ---------------- setup: basis ----------------

__global__ __launch_bounds__(256) void basis_kernel(
    const float* __restrict__ nodes, const float* __restrict__ nw,
    const float* __restrict__ modes, const float* __restrict__ latent,
    unsigned short* __restrict__ bcb, unsigned short* __restrict__ bsb,
    unsigned short* __restrict__ wBt)
{
    __shared__ float lx[64], ly[64], lz[64], lwv[64];
    __shared__ unsigned short lTc[32*64], lTs[32*64];
    int b = blockIdx.y, n0 = blockIdx.x*64;
    int tid = threadIdx.x;
    size_t bN = (size_t)b*N_;
    if (tid < 64){
        int n = n0 + tid;
        float iL0 = 0.5f + 1.5f/(1.f+expf(-latent[0]));
        float iL1 = 0.5f + 1.5f/(1.f+expf(-latent[1]));
        float iL2 = 0.5f + 1.5f/(1.f+expf(-latent[2]));
        if (n < N_){
            lx[tid] = nodes[(bN+n)*3+0]*iL0;
            ly[tid] = nodes[(bN+n)*3+1]*iL1;
            lz[tid] = nodes[(bN+n)*3+2]*iL2;
            lwv[tid] = nw[bN+n];
        } else { lx[tid]=0.f; ly[tid]=0.f; lz[tid]=0.f; lwv[tid]=0.f; }
    }
    __syncthreads();
    int node = tid>>2, k0 = (tid&3)*8;
    float p0 = lx[node], p1 = ly[node], p2 = lz[node], w = lwv[node];
    float cv[8], sv[8];
    #pragma unroll
    for (int i=0;i<8;i++){
        int k = k0+i;
        float t = p0*modes[k*3+0] + p1*modes[k*3+1] + p2*modes[k*3+2];
        cv[i] = cosf(t); sv[i] = sinf(t);
        lTc[k*64 + node] = f2bf(w*cv[i]);
        lTs[k*64 + node] = f2bf(w*sv[i]);
    }
    int gn = n0 + node;
    if (gn < N_){
        uintx4 uc = (uintx4){pack2(cv[0],cv[1]), pack2(cv[2],cv[3]),
                             pack2(cv[4],cv[5]), pack2(cv[6],cv[7])};
        uintx4 us = (uintx4){pack2(sv[0],sv[1]), pack2(sv[2],sv[3]),
                             pack2(sv[4],sv[5]), pack2(sv[6],sv[7])};
        *(uintx4*)&bcb[(bN+gn)*K_ + k0] = uc;
        *(uintx4*)&bsb[(bN+gn)*K_ + k0] = us;
    }
    __syncthreads();
    #pragma unroll
    for (int i=0;i<5;i++){
        int idx = i*256 + tid;   // < 1280
        int row = idx>>4, seg = idx&15;
        unsigned short v0,v1,v2,v3;
        if (row < 32){
            v0=lTc[row*64+seg*4+0]; v1=lTc[row*64+seg*4+1];
            v2=lTc[row*64+seg*4+2]; v3=lTc[row*64+seg*4+3];
        } else if (row < 64){
            int r = row-32;
            v0=lTs[r*64+seg*4+0]; v1=lTs[r*64+seg*4+1];
            v2=lTs[r*64+seg*4+2]; v3=lTs[r*64+seg*4+3];
        } else if (row == 64){
            v0=f2bf(lwv[seg*4+0]); v1=f2bf(lwv[seg*4+1]);
            v2=f2bf(lwv[seg*4+2]); v3=f2bf(lwv[seg*4+3]);
        } else { v0=v1=v2=v3=0; }
        uintx2 u;
        u.x = (unsigned int)v0 | ((unsigned int)v1<<16);
        u.y = (unsigned int)v2 | ((unsigned int)v3<<16);
        *(uintx2*)&wBt[((size_t)b*80+row)*NPAD + n0 + seg*4] = u;
    }
}

// ---------------- setup: fc0 (R12: LDS transpose, vectorized hT writes) ----------
// Block = 64 nodes. Phase 1: thread (node, c-quarter) computes 32 channels,
// writes hN via 16-B stores and drops bf16 into Ht[c][node] (pitch 72 keeps
// phase-2 reads 16-B aligned; transpose-write conflicts ~4-way, cheap).
// Phase 2: thread (c, half) writes 64 B of the hT row. Pad nodes produce
// exact zeros through the same path (preserves stageA's unguarded-read
// invariant).

__global__ __launch_bounds__(256) void fc0_kernel(
    const float* __restrict__ x, const float* __restrict__ w,
    const float* __restrict__ bvec, unsigned short* __restrict__ hN,
    unsigned short* __restrict__ hT)
{
    __shared__ unsigned short Ht[128*72];
    int b = blockIdx.y, n0 = blockIdx.x*64;
    int tid = threadIdx.x;
    int node = tid>>2, c0 = (tid&3)*32;
    int n = n0 + node;
    bool valid = n < N_;
    size_t idn = (size_t)b*N_ + n;
    float x0=0.f, x1=0.f, x2=0.f;
    if (valid){ x0 = x[idn*3+0]; x1 = x[idn*3+1]; x2 = x[idn*3+2]; }
    unsigned short hv[32];
    #pragma unroll
    for (int i=0;i<32;i++){
        int c = c0+i;
        float v = valid ? (bvec[c] + x0*w[c*3+0] + x1*w[c*3+1] + x2*w[c*3+2]) : 0.f;
        unsigned short bf = f2bf(v);
        hv[i] = bf;
        Ht[c*72 + node] = bf;
    }
    if (valid){
        #pragma unroll
        for (int i=0;i<4;i++)
            *(uintx4*)&hN[idn*C_ + c0 + i*8] = *(uintx4*)&hv[i*8];
    }
    __syncthreads();
    int c = tid>>1, half = tid&1;
    const unsigned short* src = &Ht[c*72 + half*32];
    unsigned short* dst = &hT[((size_t)b*C_ + c)*NPAD + n0 + half*32];
    *(uintx4*)&dst[0]  = *(const uintx4*)&src[0];
    *(uintx4*)&dst[8]  = *(const uintx4*)&src[8];
    *(uintx4*)&dst[16] = *(const uintx4*)&src[16];
    *(uintx4*)&dst[24] = *(const uintx4*)&src[24];
}

// ---------------- CSR build ----------------

__global__ __launch_bounds__(256) void hist_kernel(
    const int* __restrict__ edges, int* __restrict__ cnt)
{
    int idx = blockIdx.x*256 + threadIdx.x;
    if (idx >= B_*E_) return;
    int b = idx / E_;
    int t = edges[(size_t)idx*2];
    atomicAdd(cnt + b*N_ + t, 1);
}

__global__ __launch_bounds__(1024) void scan_kernel(
    const int* __restrict__ cnt, int* __restrict__ rowptr, int* __restrict__ cur)
{
    __shared__ int wsum[16];
    int b = blockIdx.x, tid = threadIdx.x;
    int lane = tid & 63, wv = tid >> 6;
    const int CHUNK = 20;
    int start = tid * CHUNK;
    int lc[CHUNK];
    int lsum = 0;
    #pragma unroll
    for (int i=0;i<CHUNK;i++){
        int n = start + i;
        int v = (n < N_) ? cnt[b*N_+n] : 0;
        lc[i] = v; lsum += v;
    }
    int v = lsum;
    #pragma unroll
    for (int off=1; off<64; off<<=1){
        int t = __shfl_up(v, off, 64);
        if (lane >= off) v += t;
    }
    if (lane == 63) wsum[wv] = v;
    __syncthreads();
    if (wv == 0 && lane < 16){
        int wv2 = wsum[lane];
        #pragma unroll
        for (int off=1; off<16; off<<=1){
            int t = __shfl_up(wv2, off, 64);
            if (lane >= off) wv2 += t;
        }
        wsum[lane] = wv2;
    }
    __syncthreads();
    int waveoff = (wv == 0) ? 0 : wsum[wv-1];
    int excl = waveoff + v - lsum;
    #pragma unroll
    for (int i=0;i<CHUNK;i++){
        int n = start + i;
        if (n < N_){
            rowptr[b*(N_+1)+n] = excl;
            cur[b*N_+n] = excl;
            excl += lc[i];
        }
    }
    if (tid == 0) rowptr[b*(N_+1)+N_] = E_;
}

// fill: build CSR-ordered packed edge records {src, w0, w1, w2} (16 B)
__global__ __launch_bounds__(256) void fill_kernel(
    const int* __restrict__ edges, const float* __restrict__ egw,
    int* __restrict__ cur, uintx4* __restrict__ epack)
{
    int idx = blockIdx.x*256 + threadIdx.x;
    if (idx >= B_*E_) return;
    int b = idx / E_;
    int t = edges[(size_t)idx*2];
    int src = edges[(size_t)idx*2+1];
    uintx4 rec;
    rec.x = (unsigned int)src;
    rec.y = __builtin_bit_cast(unsigned int, egw[(size_t)idx*3+0]);
    rec.z = __builtin_bit_cast(unsigned int, egw[(size_t)idx*3+1]);
    rec.w = __builtin_bit_cast(unsigned int, egw[(size_t)idx*3+2]);
    int pos = atomicAdd(cur + b*N_ + t, 1);
    epack[(size_t)b*E_ + pos] = rec;
}

// ---------------- weight concat f32 -> bf16 (R12: wconv+fc1conv merged) --------

__global__ __launch_bounds__(256) void wconv_kernel(
    const float* __restrict__ ww, const float* __restrict__ gw,
    const float* __restrict__ fc1w,
    unsigned short* __restrict__ wcat3, unsigned short* __restrict__ fcw16)
{
    int o = blockIdx.x, l = blockIdx.y, t = threadIdx.x;
    if (l < 3){
        const float* ww_l = ww + (size_t)l*C_*C_;
        const float* gw_l = gw + (size_t)l*C_*C_*3;
        int k = t*2;
        float a, bv;
        if (k < 128){ a = ww_l[(size_t)o*C_ + k];      bv = ww_l[(size_t)o*C_ + k + 1]; }
        else        { a = gw_l[(size_t)o*384 + k-128]; bv = gw_l[(size_t)o*384 + k-127]; }
        *(unsigned int*)&wcat3[((size_t)l*C_ + o)*512 + k] = pack2(a, bv);
    } else if (t < 64){
        int k = t*2;
        *(unsigned int*)&fcw16[(size_t)o*C_ + k] = pack2(fc1w[(size_t)o*C_+k], fc1w[(size_t)o*C_+k+1]);
    }
}

// ---------------- per-layer: spectral reduce as MFMA GEMM (split-C, counted-vmcnt) --

__global__ __launch_bounds__(256) void stageA_kernel(
    const unsigned short* __restrict__ hT, const unsigned short* __restrict__ wBt,
    float* __restrict__ part)
{
    __shared__ unsigned short stg[2][160*64];   // 2 x 20 KB = 40 KB
    int b = blockIdx.y;
    int blk = blockIdx.x >> 1;      // node-group 0..63
    int half = blockIdx.x & 1;      // c-half
    int tid = threadIdx.x;
    int wv = tid>>6, lane = tid&63, l15 = lane&15, quad = lane>>4;
    floatx4 acc[5];
    #pragma unroll
    for (int mt=0;mt<5;mt++) acc[mt]=(floatx4){0,0,0,0};
    size_t hbase = (size_t)b*C_*NPAD;
    size_t wbase = (size_t)b*80*NPAD;
    int n0 = blk*320;
    const unsigned short* sp[5];
    #pragma unroll
    for (int q=0;q<5;q++){
        int li = q*256 + tid;
        int r = li>>3;
        int u = (li&7) ^ (r&7);
        int rw = (r < 80) ? r : 79;   // clamp pad rows into wBt allocation
        sp[q] = (r < 96) ? (wBt + wbase + (size_t)rw*NPAD + n0 + u*8)
                         : (hT  + hbase + (size_t)(half*64 + r-96)*NPAD + n0 + u*8);
    }

#define SSTG(ch) do{ \
    _Pragma("unroll") \
    for (int q=0;q<5;q++) \
        __builtin_amdgcn_global_load_lds( \
            (const __attribute__((address_space(1))) void*)(sp[q] + (ch)*64), \
            (__attribute__((address_space(3))) void*)&stg[(ch)&1][q*2048 + wv*512], \
            16, 0, 0); }while(0)

#define SCOMP(ch) do{ \
    _Pragma("unroll") \
    for (int ks=0; ks<2; ks++){ \
        short8 bfrag = *(const short8*)&stg[(ch)&1][(96 + wv*16 + l15)*64 + (((ks*4+quad)^(l15&7))*8)]; \
        _Pragma("unroll") \
        for (int mt=0;mt<5;mt++){ \
            short8 af = *(const short8*)&stg[(ch)&1][(mt*16+l15)*64 + (((ks*4+quad)^(l15&7))*8)]; \
            acc[mt] = __builtin_amdgcn_mfma_f32_16x16x32_bf16(af, bfrag, acc[mt], 0,0,0); \
        } } }while(0)

    SSTG(0); SSTG(1);
    WAITV(5); BAR(); SCOMP(0); BAR(); SSTG(2);
    WAITV(5); BAR(); SCOMP(1); BAR(); SSTG(3);
    WAITV(5); BAR(); SCOMP(2); BAR(); SSTG(4);
    WAITV(5); BAR(); SCOMP(3);
    WAITV(0); BAR(); SCOMP(4);
#undef SSTG
#undef SCOMP

    float* pblk = part + ((size_t)(b*64+blk))*80*C_;
    int cg = half*64 + wv*16 + l15;
    #pragma unroll
    for (int mt=0;mt<5;mt++){
        #pragma unroll
        for (int r=0;r<4;r++){
            int kcol = mt*16 + quad*4 + r;
            pblk[kcol*C_ + cg] = acc[mt][r];
        }
    }
}

// writes TRANSPOSED xqT[b][c][kcol] (c-major) so mix's reads coalesce.
__global__ __launch_bounds__(256) void reducePart_kernel(
    const float* __restrict__ part, float* __restrict__ xqT)
{
    int idx = blockIdx.x*256 + threadIdx.x;
    if (idx >= B_*80*C_) return;
    int b = idx / (80*C_);
    int r = idx - b*80*C_;          // r = kcol*C + c
    int kcol = r >> 7, c = r & 127;
    float s = 0.f;
    #pragma unroll 8
    for (int blk=0; blk<64; blk++)
        s += part[((size_t)(b*64+blk))*80*C_ + r];
    xqT[(size_t)b*80*C_ + c*80 + kcol] = s;
}

// ---------------- per-layer: mode mixing (coalesced via xqT) ----------------

__global__ __launch_bounds__(64) void mix_kernel(
    const float* __restrict__ xqT, const float* __restrict__ swc_l,
    const float* __restrict__ sws_l, const float* __restrict__ sw0_l,
    unsigned short* __restrict__ wfb, float* __restrict__ f0)
{
    int o = blockIdx.x, b = blockIdx.y;
    int t = threadIdx.x;
    int k = t & 31; bool isS = t >= 32;
    const float* xqb = xqT + (size_t)b*80*C_;
    float acc = 0.f;
    #pragma unroll 4
    for (int c=0;c<C_;c++){
        float xc = xqb[c*80 + k];
        float xs = xqb[c*80 + 32 + k];
        float wc = swc_l[((size_t)c*C_+o)*K_ + k];
        float ws = sws_l[((size_t)c*C_+o)*K_ + k];
        acc += isS ? (xs*wc + xc*ws) : (xc*wc - xs*ws);
    }
    wfb[((size_t)b*C_+o)*64 + t] = f2bf(isS ? -2.f*acc : 2.f*acc);
    float p = xqb[t*80 + 64]        * sw0_l[(size_t)t*C_+o]
            + xqb[(t+64)*80 + 64]   * sw0_l[(size_t)(t+64)*C_+o];
    #pragma unroll
    for (int m=1;m<64;m<<=1) p += __shfl_xor(p, m, 64);
    if (t==0) f0[(size_t)b*C_+o] = p;
}

// ---------------- per-layer: gradient gather (packed CSR), XCD-swizzled ----------------

__global__ __launch_bounds__(256) void grad_kernel(
    const unsigned short* __restrict__ hN, const uintx4* __restrict__ epack,
    const int* __restrict__ rowptr, unsigned short* __restrict__ g)
{
    int flat = blockIdx.x;              // 20000 blocks
    int xcd = flat & 7;
    int b = xcd >> 1;
    int grp = (flat >> 3)*2 + (xcd & 1);    // 0..4999 within batch
    int n = grp*4 + (threadIdx.x >> 6);
    int cp = threadIdx.x & 63;
    size_t bN = (size_t)b*N_;
    size_t bE = (size_t)b*E_;
    int r0 = rowptr[b*(N_+1)+n], r1 = rowptr[b*(N_+1)+n+1];
    unsigned int hcu = *(const unsigned int*)&hN[(bN+n)*C_ + cp*2];
    float hc0 = bf2f((unsigned short)hcu), hc1 = bf2f((unsigned short)(hcu>>16));
    float a00=0.f,a01=0.f,a02=0.f, a10=0.f,a11=0.f,a12=0.f;
    int i = r0;
    for (; i + 3 < r1; i += 4){
        uintx4 p0 = epack[bE + i];
        uintx4 p1 = epack[bE + i + 1];
        uintx4 p2 = epack[bE + i + 2];
        uintx4 p3 = epack[bE + i + 3];
        unsigned int u0 = *(const unsigned int*)&hN[(bN+(int)p0.x)*C_ + cp*2];
        unsigned int u1 = *(const unsigned int*)&hN[(bN+(int)p1.x)*C_ + cp*2];
        unsigned int u2 = *(const unsigned int*)&hN[(bN+(int)p2.x)*C_ + cp*2];
        unsigned int u3 = *(const unsigned int*)&hN[(bN+(int)p3.x)*C_ + cp*2];
        float d00 = bf2f((unsigned short)u0) - hc0, d01 = bf2f((unsigned short)(u0>>16)) - hc1;
        float d10 = bf2f((unsigned short)u1) - hc0, d11 = bf2f((unsigned short)(u1>>16)) - hc1;
        float d20 = bf2f((unsigned short)u2) - hc0, d21 = bf2f((unsigned short)(u2>>16)) - hc1;
        float d30 = bf2f((unsigned short)u3) - hc0, d31 = bf2f((unsigned short)(u3>>16)) - hc1;
        a00 += u2f(p0.y)*d00; a01 += u2f(p0.z)*d00; a02 += u2f(p0.w)*d00;
        a10 += u2f(p0.y)*d01; a11 += u2f(p0.z)*d01; a12 += u2f(p0.w)*d01;
        a00 += u2f(p1.y)*d10; a01 += u2f(p1.z)*d10; a02 += u2f(p1.w)*d10;
        a10 += u2f(p1.y)*d11; a11 += u2f(p1.z)*d11; a12 += u2f(p1.w)*d11;
        a00 += u2f(p2.y)*d20; a01 += u2f(p2.z)*d20; a02 += u2f(p2.w)*d20;
        a10 += u2f(p2.y)*d21; a11 += u2f(p2.z)*d21; a12 += u2f(p2.w)*d21;
        a00 += u2f(p3.y)*d30; a01 += u2f(p3.z)*d30; a02 += u2f(p3.w)*d30;
        a10 += u2f(p3.y)*d31; a11 += u2f(p3.z)*d31; a12 += u2f(p3.w)*d31;
    }
    for (; i < r1; ++i){
        uintx4 p0 = epack[bE + i];
        unsigned int u0 = *(const unsigned int*)&hN[(bN+(int)p0.x)*C_ + cp*2];
        float w00 = u2f(p0.y), w01 = u2f(p0.z), w02 = u2f(p0.w);
        float d00 = bf2f((unsigned short)u0) - hc0;
        float d01 = bf2f((unsigned short)(u0>>16)) - hc1;
        a00 += w00*d00; a01 += w01*d00; a02 += w02*d00;
        a10 += w00*d01; a11 += w01*d01; a12 += w02*d01;
    }
    unsigned short* gr = g + (bN+n)*(size_t)384 + cp*6;
    *(unsigned int*)(gr+0) = pack2(a00,a01);
    *(unsigned int*)(gr+2) = pack2(a02,a10);
    *(unsigned int*)(gr+4) = pack2(a11,a12);
}

// ---------------- per-layer: fused MFMA GEMM (K=576) ----------------
// R12: epilogue v2 — AsF LDS tile built for ALL layers; hNo written as
// 4 x 16-B stores per thread from AsF columns (conflict-free: per
// instruction lanes walk n at 2 B = 2 lanes/word). Replaces 32 scalar
// 2-B global stores per thread (16x fewer store instructions). hT path
// unchanged (rows of AsF). K-loop and vmcnt ledger untouched.

__global__ __launch_bounds__(256) void gemm_kernel(
    const unsigned short* __restrict__ hN, const unsigned short* __restrict__ g,
    const unsigned short* __restrict__ bcb, const unsigned short* __restrict__ bsb,
    const unsigned short* __restrict__ wcat, const unsigned short* __restrict__ wfb,
    const float* __restrict__ wb_l, const float* __restrict__ gb_l,
    const float* __restrict__ f0,
    unsigned short* __restrict__ hNo, unsigned short* __restrict__ hT, int apply_gelu)
{
    __shared__ unsigned short As4[4][4096];   // 4 bufs x (64 rows x 128 B) = 32 KB
    int b = blockIdx.y;
    int nb0 = blockIdx.x*64;
    int tid = threadIdx.x;
    int wv = tid>>6, lane = tid&63, l15 = lane&15, quad = lane>>4;
    floatx4 acc[4][2];
    #pragma unroll
    for (int mt=0;mt<4;mt++)
        #pragma unroll
        for (int ot=0;ot<2;ot++) acc[mt][ot] = (floatx4){0.f,0.f,0.f,0.f};
    size_t bN = (size_t)b*N_;

    const unsigned short* sh[2]; const unsigned short* sg[2]; const unsigned short* sb[2];
    #pragma unroll
    for (int q=0;q<2;q++){
        int li = q*256 + tid;
        int row = li>>3, col = (li&7) ^ (row&7);
        size_t gr = bN + (size_t)(nb0 + row);
        sh[q] = hN + gr*C_  + col*8;
        sg[q] = g  + gr*384 + col*8;
        sb[q] = (col < 4) ? (bcb + gr*K_ + col*8) : (bsb + gr*K_ + (col-4)*8);
    }
    int o0 = wv*32 + l15, o1 = o0 + 16;
    const unsigned short* w0p = wcat + (size_t)o0*512 + quad*8;
    const unsigned short* w1p = wcat + (size_t)o1*512 + quad*8;
    const unsigned short* fb0 = wfb + ((size_t)b*C_ + o0)*64 + quad*8;
    const unsigned short* fb1 = wfb + ((size_t)b*C_ + o1)*64 + quad*8;

    short8 bb[3][2][2];

#define LOADB(ch) do{ \
    if ((ch) < 8){ \
        bb[(ch)%3][0][0] = *(const short8*)(w0p + (ch)*64); \
        bb[(ch)%3][0][1] = *(const short8*)(w0p + (ch)*64 + 32); \
        bb[(ch)%3][1][0] = *(const short8*)(w1p + (ch)*64); \
        bb[(ch)%3][1][1] = *(const short8*)(w1p + (ch)*64 + 32); \
    } else { \
        bb[(ch)%3][0][0] = *(const short8*)(fb0); \
        bb[(ch)%3][0][1] = *(const short8*)(fb0 + 32); \
        bb[(ch)%3][1][0] = *(const short8*)(fb1); \
        bb[(ch)%3][1][1] = *(const short8*)(fb1 + 32); \
    } }while(0)

#define STAGE1(ch,q) \
    __builtin_amdgcn_global_load_lds( \
        (const __attribute__((address_space(1))) void*)( \
            ((ch) < 2) ? (sh[q] + (ch)*64) : \
            ((ch) < 8) ? (sg[q] + ((ch)-2)*64) : sb[q] ), \
        (__attribute__((address_space(3))) void*)&As4[(ch)&3][(q)*2048 + wv*512], \
        16, 0, 0)
#define STAGE(ch) do{ STAGE1(ch,0); STAGE1(ch,1); }while(0)

#define COMPUTE(ch) do{ \
    _Pragma("unroll") \
    for (int ks=0; ks<2; ks++){ \
        _Pragma("unroll") \
        for (int mt=0; mt<4; mt++){ \
            short8 af = *(const short8*)&As4[(ch)&3][(mt*16+l15)*64 + (((ks*4+quad)^(l15&7))*8)]; \
            acc[mt][0] = __builtin_amdgcn_mfma_f32_16x16x32_bf16(af, bb[(ch)%3][0][ks], acc[mt][0], 0,0,0); \
            acc[mt][1] = __builtin_amdgcn_mfma_f32_16x16x32_bf16(af, bb[(ch)%3][1][ks], acc[mt][1], 0,0,0); \
        } } }while(0)

    LOADB(0); LOADB(1);
    STAGE(0); STAGE(1); STAGE(2);
    WAITV(4); BAR(); LOADB(2); STAGE(3); COMPUTE(0);
    WAITV(8); BAR(); LOADB(3); STAGE(4); COMPUTE(1);
    WAITV(8); BAR(); LOADB(4); STAGE(5); COMPUTE(2);
    WAITV(8); BAR(); LOADB(5); STAGE(6); COMPUTE(3);
    WAITV(8); BAR(); LOADB(6); STAGE(7); COMPUTE(4);
    WAITV(8); BAR(); LOADB(7); STAGE(8); COMPUTE(5);
    WAITV(8); BAR(); LOADB(8);           COMPUTE(6);
    WAITV(6); BAR();                     COMPUTE(7);
    WAITV(0); BAR();                     COMPUTE(8);

#undef LOADB
#undef STAGE1
#undef STAGE
#undef COMPUTE

    float biasv[2]; int oo[2];
    oo[0]=o0; oo[1]=o1;
    #pragma unroll
    for (int ot=0;ot<2;ot++)
        biasv[ot] = wb_l[oo[ot]] + gb_l[oo[ot]] + f0[(size_t)b*C_ + oo[ot]];
    unsigned short* AsF = &As4[0][0];   // [o][72] tile, 18.4 KB of the 32 KB
    __syncthreads();                    // all waves done reading buf0 (chunk 8)
    #pragma unroll
    for (int mt=0;mt<4;mt++){
        #pragma unroll
        for (int ot=0;ot<2;ot++){
            int nb = nb0 + mt*16 + quad*4;
            float v4[4];
            #pragma unroll
            for (int r=0;r<4;r++){
                float vv = acc[mt][ot][r] + biasv[ot];
                if (apply_gelu) vv = gelu_exact(vv);
                v4[r] = (nb + r < N_) ? vv : 0.f;   // pad rows -> exact zeros
            }
            uintx2 u; u.x = pack2(v4[0],v4[1]); u.y = pack2(v4[2],v4[3]);
            *(uintx2*)&AsF[oo[ot]*72 + mt*16 + quad*4] = u;
        }
    }
    __syncthreads();
    {   // hNo: thread -> row nl, 32-channel group og; 4 x 16-B stores
        int nl = tid & 63, og = (tid>>6)*32;
        int n = nb0 + nl;
        if (n < N_){
            unsigned short buf[32];
            #pragma unroll
            for (int j=0;j<32;j++) buf[j] = AsF[(og+j)*72 + nl];
            unsigned short* dst = hNo + (bN+n)*C_ + og;
            *(uintx4*)&dst[0]  = *(uintx4*)&buf[0];
            *(uintx4*)&dst[8]  = *(uintx4*)&buf[8];
            *(uintx4*)&dst[16] = *(uintx4*)&buf[16];
            *(uintx4*)&dst[24] = *(uintx4*)&buf[24];
        }
    }
    if (apply_gelu){
        int orow = tid>>1, half = tid&1;
        uintx4 u0 = *(const uintx4*)&AsF[orow*72 + half*32];
        uintx4 u1 = *(const uintx4*)&AsF[orow*72 + half*32 + 8];
        unsigned short* dst = &hT[((size_t)b*C_ + orow)*NPAD + nb0 + half*32];
        *(uintx4*)dst       = u0;
        *(uintx4*)(dst + 8) = u1;
    }
}

// ---------------- head: MFMA fc1 + gelu + fc2 (counted-vmcnt staging) ----------

__global__ __launch_bounds__(256) void final_kernel(
    const unsigned short* __restrict__ hN, const unsigned short* __restrict__ fc1b16,
    const float* __restrict__ fc1b, const float* __restrict__ fc2w,
    const float* __restrict__ fc2b, float* __restrict__ out)
{
    __shared__ unsigned short Fs[2][4096];   // 2 bufs x (64 rows x 128 B)
    __shared__ float pp[4*64];
    int b = blockIdx.y;
    int nb0 = blockIdx.x*64;
    int tid = threadIdx.x;
    int wv = tid>>6, lane = tid&63, l15 = lane&15, quad = lane>>4;
    floatx4 acc[4][2];
    #pragma unroll
    for (int mt=0;mt<4;mt++){ acc[mt][0]=(floatx4){0,0,0,0}; acc[mt][1]=(floatx4){0,0,0,0}; }
    size_t bN = (size_t)b*N_;
    const unsigned short* sfp[2];
    #pragma unroll
    for (int q=0;q<2;q++){
        int li = q*256 + tid;
        int row = li>>3, u = (li&7) ^ (row&7);
        sfp[q] = hN + (bN + (size_t)(nb0 + row))*C_ + u*8;
    }
    int o0 = wv*32 + l15, o1 = o0 + 16;
    const unsigned short* w0p = fc1b16 + (size_t)o0*C_ + quad*8;
    const unsigned short* w1p = fc1b16 + (size_t)o1*C_ + quad*8;

#define FSTG(ch) do{ \
    _Pragma("unroll") \
    for (int q=0;q<2;q++) \
        __builtin_amdgcn_global_load_lds( \
            (const __attribute__((address_space(1))) void*)(sfp[q] + (ch)*64), \
            (__attribute__((address_space(3))) void*)&Fs[ch][q*2048 + wv*512], \
            16, 0, 0); }while(0)

#define FCOMP(ch) do{ \
    _Pragma("unroll") \
    for (int ks=0; ks<2; ks++){ \
        short8 bfr0 = *(const short8*)(w0p + (ch)*64 + ks*32); \
        short8 bfr1 = *(const short8*)(w1p + (ch)*64 + ks*32); \
        _Pragma("unroll") \
        for (int mt=0; mt<4; mt++){ \
            short8 af = *(const short8*)&Fs[ch][(mt*16+l15)*64 + (((ks*4+quad)^(l15&7))*8)]; \
            acc[mt][0] = __builtin_amdgcn_mfma_f32_16x16x32_bf16(af, bfr0, acc[mt][0], 0,0,0); \
            acc[mt][1] = __builtin_amdgcn_mfma_f32_16x16x32_bf16(af, bfr1, acc[mt][1], 0,0,0); \
        } } }while(0)

    FSTG(0); FSTG(1);
    WAITV(2); BAR(); FCOMP(0);
    WAITV(0); BAR(); FCOMP(1);
#undef FSTG
#undef FCOMP

    float fw0 = fc2w[o0], fw1 = fc2w[o1];
    float b0 = fc1b[o0], b1 = fc1b[o1];
    #pragma unroll
    for (int mt=0;mt<4;mt++){
        float s[4];
        #pragma unroll
        for (int r=0;r<4;r++)
            s[r] = fw0*gelu_exact(acc[mt][0][r] + b0) + fw1*gelu_exact(acc[mt][1][r] + b1);
        #pragma unroll
        for (int m=1;m<16;m<<=1)
            #pragma unroll
            for (int r=0;r<4;r++)
                s[r] += __shfl_xor(s[r], m, 16);
        if (l15 < 4){
            float v = (l15==0)?s[0]:(l15==1)?s[1]:(l15==2)?s[2]:s[3];
            pp[wv*64 + mt*16 + quad*4 + l15] = v;
        }
    }
    __syncthreads();
    if (tid < 64){
        float sum = pp[tid] + pp[64+tid] + pp[128+tid] + pp[192+tid] + fc2b[0];
        int n = nb0 + tid;
        if (n < N_) out[bN + n] = sum;
    }
}

// ---------------- launch ----------------

extern "C" void kernel_launch(void* const* d_in, const int* in_sizes, int n_in,
                              void* d_out, int out_size, void* d_ws, size_t ws_size,
                              hipStream_t stream)
{
    const float* x      = (const float*)d_in[0];
    const float* nodes  = (const float*)d_in[2];
    const float* nw     = (const float*)d_in[3];
    const int*   edges  = (const int*)  d_in[4];
    const float* egw    = (const float*)d_in[5];
    const float* modes  = (const float*)d_in[6];
    const float* latent = (const float*)d_in[7];
    const float* fc0w   = (const float*)d_in[8];
    const float* fc0b   = (const float*)d_in[9];
    const float* swc    = (const float*)d_in[10];
    const float* sws    = (const float*)d_in[11];
    const float* sw0    = (const float*)d_in[12];
    const float* ww     = (const float*)d_in[13];
    const float* wb     = (const float*)d_in[14];
    const float* gw     = (const float*)d_in[15];
    const float* gb     = (const float*)d_in[16];
    const float* fc1w   = (const float*)d_in[17];
    const float* fc1b   = (const float*)d_in[18];
    const float* fc2w   = (const float*)d_in[19];
    const float* fc2b   = (const float*)d_in[20];
    float* out = (float*)d_out;

    char* W = (char*)d_ws;
    size_t off = 0;
    unsigned short* bcB = (unsigned short*)(W+off); off += (size_t)NROWS*K_*2;
    unsigned short* bsB = (unsigned short*)(W+off); off += (size_t)NROWS*K_*2;
    unsigned short* wBt = (unsigned short*)(W+off); off += (size_t)B_*80*NPAD*2;
    unsigned short* hT  = (unsigned short*)(W+off); off += (size_t)B_*C_*NPAD*2;
    unsigned short* hNa = (unsigned short*)(W+off); off += (size_t)NROWS*C_*2;
    unsigned short* hNb = (unsigned short*)(W+off); off += (size_t)NROWS*C_*2;
    unsigned short* g   = (unsigned short*)(W+off); off += (size_t)NROWS*C_*3*2;
    unsigned short* wcat3=(unsigned short*)(W+off); off += (size_t)3*C_*512*2;
    unsigned short* wfb = (unsigned short*)(W+off); off += (size_t)B_*C_*64*2;
    unsigned short* fcw16=(unsigned short*)(W+off); off += (size_t)C_*C_*2;
    float* part = (float*)(W+off); off += (size_t)B_*64*80*C_*4;
    float* xq   = (float*)(W+off); off += (size_t)B_*80*C_*4;
    float* f0   = (float*)(W+off); off += (size_t)B_*C_*4;
    off = (off + 15) & ~(size_t)15;
    uintx4* epack = (uintx4*)(W+off); off += (size_t)B_*E_*16;
    int* cnt    = (int*)(W+off); off += (size_t)B_*N_*4;
    int* rowptr = (int*)(W+off); off += (size_t)B_*(N_+1)*4 + 16;
    int* cur    = (int*)(W+off); off += (size_t)B_*N_*4;

    (void)hipMemsetAsync(cnt, 0, (size_t)B_*N_*sizeof(int), stream);
    basis_kernel<<<dim3(NPAD/64, B_), 256, 0, stream>>>(
        nodes, nw, modes, latent, bcB, bsB, wBt);
    fc0_kernel  <<<dim3(NPAD/64, B_), 256, 0, stream>>>(x, fc0w, fc0b, hNa, hT);
    hist_kernel <<<(B_*E_+255)/256, 256, 0, stream>>>(edges, cnt);
    scan_kernel <<<B_, 1024, 0, stream>>>(cnt, rowptr, cur);
    fill_kernel <<<(B_*E_+255)/256, 256, 0, stream>>>(edges, egw, cur, epack);
    wconv_kernel<<<dim3(C_,4), 256, 0, stream>>>(ww, gw, fc1w, wcat3, fcw16);

    unsigned short* hc = hNa; unsigned short* hn = hNb;
    for (int l=0; l<3; ++l){
        stageA_kernel<<<dim3(128,B_), 256, 0, stream>>>(hT, wBt, part);
        reducePart_kernel<<<(B_*80*C_+255)/256, 256, 0, stream>>>(part, xq);
        mix_kernel<<<dim3(C_,B_), 64, 0, stream>>>(
            xq, swc + (size_t)l*C_*C_*K_, sws + (size_t)l*C_*C_*K_,
            sw0 + (size_t)l*C_*C_, wfb, f0);
        grad_kernel<<<N_, 256, 0, stream>>>(hc, epack, rowptr, g);
        gemm_kernel<<<dim3((N_+63)/64,B_), 256, 0, stream>>>(
            hc, g, bcB, bsB, wcat3 + (size_t)l*C_*512, wfb,
            wb + (size_t)l*C_, gb + (size_t)l*C_,
            f0, hn, hT, (l<2) ? 1 : 0);
        unsigned short* t = hc; hc = hn; hn = t;
    }
    final_kernel<<<dim3((N_+63)/64,B_), 256, 0, stream>>>(
        hc, fcw16, fc1b, fc2w, fc2b, out);
}

// Round 9
// 512.971 us; speedup vs baseline: 1.0629x; 1.0629x over previous
//
#include <hip/hip_runtime.h>
#include <math.h>

#define B_ 4
#define N_ 20000
#define E_ 100000
#define C_ 128
#define K_ 32
#define NPAD 20480   // padded node count (multiple of 64)
#define NROWS (B_*N_ + 128)   // row slack so unguarded tile reads stay in-bounds

typedef __attribute__((ext_vector_type(8))) short short8;
typedef __attribute__((ext_vector_type(4))) float floatx4;
typedef __attribute__((ext_vector_type(4))) unsigned int uintx4;
typedef __attribute__((ext_vector_type(2))) unsigned int uintx2;

__device__ __forceinline__ float gelu_exact(float x){
    return 0.5f * x * (1.0f + erff(x * 0.70710678118654752f));
}

__device__ __forceinline__ unsigned short f2bf(float f){
    unsigned int u = __builtin_bit_cast(unsigned int, f);
    u += 0x7FFFu + ((u >> 16) & 1u);   // RNE
    return (unsigned short)(u >> 16);
}
__device__ __forceinline__ unsigned int pack2(float a, float b){
    return (unsigned int)f2bf(a) | ((unsigned int)f2bf(b) << 16);
}
__device__ __forceinline__ float bf2f(unsigned short u){
    unsigned int v = ((unsigned int)u) << 16;
    return __builtin_bit_cast(float, v);
}
__device__ __forceinline__ float u2f(unsigned int u){
    return __builtin_bit_cast(float, u);
}

#define WAITV(n) asm volatile("s_waitcnt vmcnt(" #n ")" ::: "memory")
#define BAR() __builtin_amdgcn_s_barrier()

// ---------------- setup: basis ----------------

__global__ __launch_bounds__(256) void basis_kernel(
    const float* __restrict__ nodes, const float* __restrict__ nw,
    const float* __restrict__ modes, const float* __restrict__ latent,
    unsigned short* __restrict__ bcb, unsigned short* __restrict__ bsb,
    unsigned short* __restrict__ wBt)
{
    __shared__ float lx[64], ly[64], lz[64], lwv[64];
    __shared__ unsigned short lTc[32*64], lTs[32*64];
    int b = blockIdx.y, n0 = blockIdx.x*64;
    int tid = threadIdx.x;
    size_t bN = (size_t)b*N_;
    if (tid < 64){
        int n = n0 + tid;
        float iL0 = 0.5f + 1.5f/(1.f+expf(-latent[0]));
        float iL1 = 0.5f + 1.5f/(1.f+expf(-latent[1]));
        float iL2 = 0.5f + 1.5f/(1.f+expf(-latent[2]));
        if (n < N_){
            lx[tid] = nodes[(bN+n)*3+0]*iL0;
            ly[tid] = nodes[(bN+n)*3+1]*iL1;
            lz[tid] = nodes[(bN+n)*3+2]*iL2;
            lwv[tid] = nw[bN+n];
        } else { lx[tid]=0.f; ly[tid]=0.f; lz[tid]=0.f; lwv[tid]=0.f; }
    }
    __syncthreads();
    int node = tid>>2, k0 = (tid&3)*8;
    float p0 = lx[node], p1 = ly[node], p2 = lz[node], w = lwv[node];
    float cv[8], sv[8];
    #pragma unroll
    for (int i=0;i<8;i++){
        int k = k0+i;
        float t = p0*modes[k*3+0] + p1*modes[k*3+1] + p2*modes[k*3+2];
        cv[i] = cosf(t); sv[i] = sinf(t);
        lTc[k*64 + node] = f2bf(w*cv[i]);
        lTs[k*64 + node] = f2bf(w*sv[i]);
    }
    int gn = n0 + node;
    if (gn < N_){
        uintx4 uc = (uintx4){pack2(cv[0],cv[1]), pack2(cv[2],cv[3]),
                             pack2(cv[4],cv[5]), pack2(cv[6],cv[7])};
        uintx4 us = (uintx4){pack2(sv[0],sv[1]), pack2(sv[2],sv[3]),
                             pack2(sv[4],sv[5]), pack2(sv[6],sv[7])};
        *(uintx4*)&bcb[(bN+gn)*K_ + k0] = uc;
        *(uintx4*)&bsb[(bN+gn)*K_ + k0] = us;
    }
    __syncthreads();
    #pragma unroll
    for (int i=0;i<5;i++){
        int idx = i*256 + tid;   // < 1280
        int row = idx>>4, seg = idx&15;
        unsigned short v0,v1,v2,v3;
        if (row < 32){
            v0=lTc[row*64+seg*4+0]; v1=lTc[row*64+seg*4+1];
            v2=lTc[row*64+seg*4+2]; v3=lTc[row*64+seg*4+3];
        } else if (row < 64){
            int r = row-32;
            v0=lTs[r*64+seg*4+0]; v1=lTs[r*64+seg*4+1];
            v2=lTs[r*64+seg*4+2]; v3=lTs[r*64+seg*4+3];
        } else if (row == 64){
            v0=f2bf(lwv[seg*4+0]); v1=f2bf(lwv[seg*4+1]);
            v2=f2bf(lwv[seg*4+2]); v3=f2bf(lwv[seg*4+3]);
        } else { v0=v1=v2=v3=0; }
        uintx2 u;
        u.x = (unsigned int)v0 | ((unsigned int)v1<<16);
        u.y = (unsigned int)v2 | ((unsigned int)v3<<16);
        *(uintx2*)&wBt[((size_t)b*80+row)*NPAD + n0 + seg*4] = u;
    }
}

// ---------------- setup: fc0 (R11 form: covers NPAD; zeroes hT pad columns) -------

__global__ __launch_bounds__(256) void fc0_kernel(
    const float* __restrict__ x, const float* __restrict__ w,
    const float* __restrict__ bvec, unsigned short* __restrict__ hN,
    unsigned short* __restrict__ hT)
{
    int idx = blockIdx.x*256 + threadIdx.x;
    if (idx >= B_*NPAD) return;
    int b = idx / NPAD, n = idx - b*NPAD;
    if (n >= N_){
        // zero hT pad columns so unguarded stageA reads are exact zeros
        for (int c=0;c<C_;c++)
            hT[((size_t)b*C_+c)*NPAD + n] = 0;
        return;
    }
    size_t idn = (size_t)b*N_ + n;
    float x0 = x[idn*3+0], x1 = x[idn*3+1], x2 = x[idn*3+2];
    unsigned short* hr = hN + idn*C_;
    for (int c=0;c<C_;c+=4){
        float4 v;
        v.x = bvec[c+0] + x0*w[(c+0)*3] + x1*w[(c+0)*3+1] + x2*w[(c+0)*3+2];
        v.y = bvec[c+1] + x0*w[(c+1)*3] + x1*w[(c+1)*3+1] + x2*w[(c+1)*3+2];
        v.z = bvec[c+2] + x0*w[(c+2)*3] + x1*w[(c+2)*3+1] + x2*w[(c+2)*3+2];
        v.w = bvec[c+3] + x0*w[(c+3)*3] + x1*w[(c+3)*3+1] + x2*w[(c+3)*3+2];
        uintx2 u; u.x = pack2(v.x,v.y); u.y = pack2(v.z,v.w);
        *(uintx2*)(hr+c) = u;
        hT[((size_t)b*C_+c+0)*NPAD + n] = f2bf(v.x);
        hT[((size_t)b*C_+c+1)*NPAD + n] = f2bf(v.y);
        hT[((size_t)b*C_+c+2)*NPAD + n] = f2bf(v.z);
        hT[((size_t)b*C_+c+3)*NPAD + n] = f2bf(v.w);
    }
}

// ---------------- CSR build ----------------

__global__ __launch_bounds__(256) void hist_kernel(
    const int* __restrict__ edges, int* __restrict__ cnt)
{
    int idx = blockIdx.x*256 + threadIdx.x;
    if (idx >= B_*E_) return;
    int b = idx / E_;
    int t = edges[(size_t)idx*2];
    atomicAdd(cnt + b*N_ + t, 1);
}

__global__ __launch_bounds__(1024) void scan_kernel(
    const int* __restrict__ cnt, int* __restrict__ rowptr, int* __restrict__ cur)
{
    __shared__ int wsum[16];
    int b = blockIdx.x, tid = threadIdx.x;
    int lane = tid & 63, wv = tid >> 6;
    const int CHUNK = 20;
    int start = tid * CHUNK;
    int lc[CHUNK];
    int lsum = 0;
    #pragma unroll
    for (int i=0;i<CHUNK;i++){
        int n = start + i;
        int v = (n < N_) ? cnt[b*N_+n] : 0;
        lc[i] = v; lsum += v;
    }
    int v = lsum;
    #pragma unroll
    for (int off=1; off<64; off<<=1){
        int t = __shfl_up(v, off, 64);
        if (lane >= off) v += t;
    }
    if (lane == 63) wsum[wv] = v;
    __syncthreads();
    if (wv == 0 && lane < 16){
        int wv2 = wsum[lane];
        #pragma unroll
        for (int off=1; off<16; off<<=1){
            int t = __shfl_up(wv2, off, 64);
            if (lane >= off) wv2 += t;
        }
        wsum[lane] = wv2;
    }
    __syncthreads();
    int waveoff = (wv == 0) ? 0 : wsum[wv-1];
    int excl = waveoff + v - lsum;
    #pragma unroll
    for (int i=0;i<CHUNK;i++){
        int n = start + i;
        if (n < N_){
            rowptr[b*(N_+1)+n] = excl;
            cur[b*N_+n] = excl;
            excl += lc[i];
        }
    }
    if (tid == 0) rowptr[b*(N_+1)+N_] = E_;
}

// fill: build CSR-ordered packed edge records {src, w0, w1, w2} (16 B)
__global__ __launch_bounds__(256) void fill_kernel(
    const int* __restrict__ edges, const float* __restrict__ egw,
    int* __restrict__ cur, uintx4* __restrict__ epack)
{
    int idx = blockIdx.x*256 + threadIdx.x;
    if (idx >= B_*E_) return;
    int b = idx / E_;
    int t = edges[(size_t)idx*2];
    int src = edges[(size_t)idx*2+1];
    uintx4 rec;
    rec.x = (unsigned int)src;
    rec.y = __builtin_bit_cast(unsigned int, egw[(size_t)idx*3+0]);
    rec.z = __builtin_bit_cast(unsigned int, egw[(size_t)idx*3+1]);
    rec.w = __builtin_bit_cast(unsigned int, egw[(size_t)idx*3+2]);
    int pos = atomicAdd(cur + b*N_ + t, 1);
    epack[(size_t)b*E_ + pos] = rec;
}

// ---------------- weight concat f32 -> bf16 (wconv+fc1conv merged) --------

__global__ __launch_bounds__(256) void wconv_kernel(
    const float* __restrict__ ww, const float* __restrict__ gw,
    const float* __restrict__ fc1w,
    unsigned short* __restrict__ wcat3, unsigned short* __restrict__ fcw16)
{
    int o = blockIdx.x, l = blockIdx.y, t = threadIdx.x;
    if (l < 3){
        const float* ww_l = ww + (size_t)l*C_*C_;
        const float* gw_l = gw + (size_t)l*C_*C_*3;
        int k = t*2;
        float a, bv;
        if (k < 128){ a = ww_l[(size_t)o*C_ + k];      bv = ww_l[(size_t)o*C_ + k + 1]; }
        else        { a = gw_l[(size_t)o*384 + k-128]; bv = gw_l[(size_t)o*384 + k-127]; }
        *(unsigned int*)&wcat3[((size_t)l*C_ + o)*512 + k] = pack2(a, bv);
    } else if (t < 64){
        int k = t*2;
        *(unsigned int*)&fcw16[(size_t)o*C_ + k] = pack2(fc1w[(size_t)o*C_+k], fc1w[(size_t)o*C_+k+1]);
    }
}

// ---------------- per-layer: spectral reduce as MFMA GEMM (split-C, counted-vmcnt) --

__global__ __launch_bounds__(256) void stageA_kernel(
    const unsigned short* __restrict__ hT, const unsigned short* __restrict__ wBt,
    float* __restrict__ part)
{
    __shared__ unsigned short stg[2][160*64];   // 2 x 20 KB = 40 KB
    int b = blockIdx.y;
    int blk = blockIdx.x >> 1;      // node-group 0..63
    int half = blockIdx.x & 1;      // c-half
    int tid = threadIdx.x;
    int wv = tid>>6, lane = tid&63, l15 = lane&15, quad = lane>>4;
    floatx4 acc[5];
    #pragma unroll
    for (int mt=0;mt<5;mt++) acc[mt]=(floatx4){0,0,0,0};
    size_t hbase = (size_t)b*C_*NPAD;
    size_t wbase = (size_t)b*80*NPAD;
    int n0 = blk*320;
    const unsigned short* sp[5];
    #pragma unroll
    for (int q=0;q<5;q++){
        int li = q*256 + tid;
        int r = li>>3;
        int u = (li&7) ^ (r&7);
        int rw = (r < 80) ? r : 79;   // clamp pad rows into wBt allocation
        sp[q] = (r < 96) ? (wBt + wbase + (size_t)rw*NPAD + n0 + u*8)
                         : (hT  + hbase + (size_t)(half*64 + r-96)*NPAD + n0 + u*8);
    }

#define SSTG(ch) do{ \
    _Pragma("unroll") \
    for (int q=0;q<5;q++) \
        __builtin_amdgcn_global_load_lds( \
            (const __attribute__((address_space(1))) void*)(sp[q] + (ch)*64), \
            (__attribute__((address_space(3))) void*)&stg[(ch)&1][q*2048 + wv*512], \
            16, 0, 0); }while(0)

#define SCOMP(ch) do{ \
    _Pragma("unroll") \
    for (int ks=0; ks<2; ks++){ \
        short8 bfrag = *(const short8*)&stg[(ch)&1][(96 + wv*16 + l15)*64 + (((ks*4+quad)^(l15&7))*8)]; \
        _Pragma("unroll") \
        for (int mt=0;mt<5;mt++){ \
            short8 af = *(const short8*)&stg[(ch)&1][(mt*16+l15)*64 + (((ks*4+quad)^(l15&7))*8)]; \
            acc[mt] = __builtin_amdgcn_mfma_f32_16x16x32_bf16(af, bfrag, acc[mt], 0,0,0); \
        } } }while(0)

    SSTG(0); SSTG(1);
    WAITV(5); BAR(); SCOMP(0); BAR(); SSTG(2);
    WAITV(5); BAR(); SCOMP(1); BAR(); SSTG(3);
    WAITV(5); BAR(); SCOMP(2); BAR(); SSTG(4);
    WAITV(5); BAR(); SCOMP(3);
    WAITV(0); BAR(); SCOMP(4);
#undef SSTG
#undef SCOMP

    float* pblk = part + ((size_t)(b*64+blk))*80*C_;
    int cg = half*64 + wv*16 + l15;
    #pragma unroll
    for (int mt=0;mt<5;mt++){
        #pragma unroll
        for (int r=0;r<4;r++){
            int kcol = mt*16 + quad*4 + r;
            pblk[kcol*C_ + cg] = acc[mt][r];
        }
    }
}

// writes TRANSPOSED xqT[b][c][kcol] (c-major) so mix's reads coalesce.
__global__ __launch_bounds__(256) void reducePart_kernel(
    const float* __restrict__ part, float* __restrict__ xqT)
{
    int idx = blockIdx.x*256 + threadIdx.x;
    if (idx >= B_*80*C_) return;
    int b = idx / (80*C_);
    int r = idx - b*80*C_;          // r = kcol*C + c
    int kcol = r >> 7, c = r & 127;
    float s = 0.f;
    #pragma unroll 8
    for (int blk=0; blk<64; blk++)
        s += part[((size_t)(b*64+blk))*80*C_ + r];
    xqT[(size_t)b*80*C_ + c*80 + kcol] = s;
}

// ---------------- per-layer: mode mixing (coalesced via xqT) ----------------

__global__ __launch_bounds__(64) void mix_kernel(
    const float* __restrict__ xqT, const float* __restrict__ swc_l,
    const float* __restrict__ sws_l, const float* __restrict__ sw0_l,
    unsigned short* __restrict__ wfb, float* __restrict__ f0)
{
    int o = blockIdx.x, b = blockIdx.y;
    int t = threadIdx.x;
    int k = t & 31; bool isS = t >= 32;
    const float* xqb = xqT + (size_t)b*80*C_;
    float acc = 0.f;
    #pragma unroll 4
    for (int c=0;c<C_;c++){
        float xc = xqb[c*80 + k];
        float xs = xqb[c*80 + 32 + k];
        float wc = swc_l[((size_t)c*C_+o)*K_ + k];
        float ws = sws_l[((size_t)c*C_+o)*K_ + k];
        acc += isS ? (xs*wc + xc*ws) : (xc*wc - xs*ws);
    }
    wfb[((size_t)b*C_+o)*64 + t] = f2bf(isS ? -2.f*acc : 2.f*acc);
    float p = xqb[t*80 + 64]        * sw0_l[(size_t)t*C_+o]
            + xqb[(t+64)*80 + 64]   * sw0_l[(size_t)(t+64)*C_+o];
    #pragma unroll
    for (int m=1;m<64;m<<=1) p += __shfl_xor(p, m, 64);
    if (t==0) f0[(size_t)b*C_+o] = p;
}

// ---------------- per-layer: gradient gather (packed CSR), XCD-swizzled ----------------

__global__ __launch_bounds__(256) void grad_kernel(
    const unsigned short* __restrict__ hN, const uintx4* __restrict__ epack,
    const int* __restrict__ rowptr, unsigned short* __restrict__ g)
{
    int flat = blockIdx.x;              // 20000 blocks
    int xcd = flat & 7;
    int b = xcd >> 1;
    int grp = (flat >> 3)*2 + (xcd & 1);    // 0..4999 within batch
    int n = grp*4 + (threadIdx.x >> 6);
    int cp = threadIdx.x & 63;
    size_t bN = (size_t)b*N_;
    size_t bE = (size_t)b*E_;
    int r0 = rowptr[b*(N_+1)+n], r1 = rowptr[b*(N_+1)+n+1];
    unsigned int hcu = *(const unsigned int*)&hN[(bN+n)*C_ + cp*2];
    float hc0 = bf2f((unsigned short)hcu), hc1 = bf2f((unsigned short)(hcu>>16));
    float a00=0.f,a01=0.f,a02=0.f, a10=0.f,a11=0.f,a12=0.f;
    int i = r0;
    for (; i + 3 < r1; i += 4){
        uintx4 p0 = epack[bE + i];
        uintx4 p1 = epack[bE + i + 1];
        uintx4 p2 = epack[bE + i + 2];
        uintx4 p3 = epack[bE + i + 3];
        unsigned int u0 = *(const unsigned int*)&hN[(bN+(int)p0.x)*C_ + cp*2];
        unsigned int u1 = *(const unsigned int*)&hN[(bN+(int)p1.x)*C_ + cp*2];
        unsigned int u2 = *(const unsigned int*)&hN[(bN+(int)p2.x)*C_ + cp*2];
        unsigned int u3 = *(const unsigned int*)&hN[(bN+(int)p3.x)*C_ + cp*2];
        float d00 = bf2f((unsigned short)u0) - hc0, d01 = bf2f((unsigned short)(u0>>16)) - hc1;
        float d10 = bf2f((unsigned short)u1) - hc0, d11 = bf2f((unsigned short)(u1>>16)) - hc1;
        float d20 = bf2f((unsigned short)u2) - hc0, d21 = bf2f((unsigned short)(u2>>16)) - hc1;
        float d30 = bf2f((unsigned short)u3) - hc0, d31 = bf2f((unsigned short)(u3>>16)) - hc1;
        a00 += u2f(p0.y)*d00; a01 += u2f(p0.z)*d00; a02 += u2f(p0.w)*d00;
        a10 += u2f(p0.y)*d01; a11 += u2f(p0.z)*d01; a12 += u2f(p0.w)*d01;
        a00 += u2f(p1.y)*d10; a01 += u2f(p1.z)*d10; a02 += u2f(p1.w)*d10;
        a10 += u2f(p1.y)*d11; a11 += u2f(p1.z)*d11; a12 += u2f(p1.w)*d11;
        a00 += u2f(p2.y)*d20; a01 += u2f(p2.z)*d20; a02 += u2f(p2.w)*d20;
        a10 += u2f(p2.y)*d21; a11 += u2f(p2.z)*d21; a12 += u2f(p2.w)*d21;
        a00 += u2f(p3.y)*d30; a01 += u2f(p3.z)*d30; a02 += u2f(p3.w)*d30;
        a10 += u2f(p3.y)*d31; a11 += u2f(p3.z)*d31; a12 += u2f(p3.w)*d31;
    }
    for (; i < r1; ++i){
        uintx4 p0 = epack[bE + i];
        unsigned int u0 = *(const unsigned int*)&hN[(bN+(int)p0.x)*C_ + cp*2];
        float w00 = u2f(p0.y), w01 = u2f(p0.z), w02 = u2f(p0.w);
        float d00 = bf2f((unsigned short)u0) - hc0;
        float d01 = bf2f((unsigned short)(u0>>16)) - hc1;
        a00 += w00*d00; a01 += w01*d00; a02 += w02*d00;
        a10 += w00*d01; a11 += w01*d01; a12 += w02*d01;
    }
    unsigned short* gr = g + (bN+n)*(size_t)384 + cp*6;
    *(unsigned int*)(gr+0) = pack2(a00,a01);
    *(unsigned int*)(gr+2) = pack2(a02,a10);
    *(unsigned int*)(gr+4) = pack2(a11,a12);
}

// ---------------- per-layer: fused MFMA GEMM (K=576), R11 form ----------------

__global__ __launch_bounds__(256) void gemm_kernel(
    const unsigned short* __restrict__ hN, const unsigned short* __restrict__ g,
    const unsigned short* __restrict__ bcb, const unsigned short* __restrict__ bsb,
    const unsigned short* __restrict__ wcat, const unsigned short* __restrict__ wfb,
    const float* __restrict__ wb_l, const float* __restrict__ gb_l,
    const float* __restrict__ f0,
    unsigned short* __restrict__ hNo, unsigned short* __restrict__ hT, int apply_gelu)
{
    __shared__ unsigned short As4[4][4096];   // 4 bufs x (64 rows x 128 B) = 32 KB
    int b = blockIdx.y;
    int nb0 = blockIdx.x*64;
    int tid = threadIdx.x;
    int wv = tid>>6, lane = tid&63, l15 = lane&15, quad = lane>>4;
    floatx4 acc[4][2];
    #pragma unroll
    for (int mt=0;mt<4;mt++)
        #pragma unroll
        for (int ot=0;ot<2;ot++) acc[mt][ot] = (floatx4){0.f,0.f,0.f,0.f};
    size_t bN = (size_t)b*N_;

    const unsigned short* sh[2]; const unsigned short* sg[2]; const unsigned short* sb[2];
    #pragma unroll
    for (int q=0;q<2;q++){
        int li = q*256 + tid;
        int row = li>>3, col = (li&7) ^ (row&7);
        size_t gr = bN + (size_t)(nb0 + row);
        sh[q] = hN + gr*C_  + col*8;
        sg[q] = g  + gr*384 + col*8;
        sb[q] = (col < 4) ? (bcb + gr*K_ + col*8) : (bsb + gr*K_ + (col-4)*8);
    }
    int o0 = wv*32 + l15, o1 = o0 + 16;
    const unsigned short* w0p = wcat + (size_t)o0*512 + quad*8;
    const unsigned short* w1p = wcat + (size_t)o1*512 + quad*8;
    const unsigned short* fb0 = wfb + ((size_t)b*C_ + o0)*64 + quad*8;
    const unsigned short* fb1 = wfb + ((size_t)b*C_ + o1)*64 + quad*8;

    short8 bb[3][2][2];

#define LOADB(ch) do{ \
    if ((ch) < 8){ \
        bb[(ch)%3][0][0] = *(const short8*)(w0p + (ch)*64); \
        bb[(ch)%3][0][1] = *(const short8*)(w0p + (ch)*64 + 32); \
        bb[(ch)%3][1][0] = *(const short8*)(w1p + (ch)*64); \
        bb[(ch)%3][1][1] = *(const short8*)(w1p + (ch)*64 + 32); \
    } else { \
        bb[(ch)%3][0][0] = *(const short8*)(fb0); \
        bb[(ch)%3][0][1] = *(const short8*)(fb0 + 32); \
        bb[(ch)%3][1][0] = *(const short8*)(fb1); \
        bb[(ch)%3][1][1] = *(const short8*)(fb1 + 32); \
    } }while(0)

#define STAGE1(ch,q) \
    __builtin_amdgcn_global_load_lds( \
        (const __attribute__((address_space(1))) void*)( \
            ((ch) < 2) ? (sh[q] + (ch)*64) : \
            ((ch) < 8) ? (sg[q] + ((ch)-2)*64) : sb[q] ), \
        (__attribute__((address_space(3))) void*)&As4[(ch)&3][(q)*2048 + wv*512], \
        16, 0, 0)
#define STAGE(ch) do{ STAGE1(ch,0); STAGE1(ch,1); }while(0)

#define COMPUTE(ch) do{ \
    _Pragma("unroll") \
    for (int ks=0; ks<2; ks++){ \
        _Pragma("unroll") \
        for (int mt=0; mt<4; mt++){ \
            short8 af = *(const short8*)&As4[(ch)&3][(mt*16+l15)*64 + (((ks*4+quad)^(l15&7))*8)]; \
            acc[mt][0] = __builtin_amdgcn_mfma_f32_16x16x32_bf16(af, bb[(ch)%3][0][ks], acc[mt][0], 0,0,0); \
            acc[mt][1] = __builtin_amdgcn_mfma_f32_16x16x32_bf16(af, bb[(ch)%3][1][ks], acc[mt][1], 0,0,0); \
        } } }while(0)

    LOADB(0); LOADB(1);
    STAGE(0); STAGE(1); STAGE(2);
    WAITV(4); BAR(); LOADB(2); STAGE(3); COMPUTE(0);
    WAITV(8); BAR(); LOADB(3); STAGE(4); COMPUTE(1);
    WAITV(8); BAR(); LOADB(4); STAGE(5); COMPUTE(2);
    WAITV(8); BAR(); LOADB(5); STAGE(6); COMPUTE(3);
    WAITV(8); BAR(); LOADB(6); STAGE(7); COMPUTE(4);
    WAITV(8); BAR(); LOADB(7); STAGE(8); COMPUTE(5);
    WAITV(8); BAR(); LOADB(8);           COMPUTE(6);
    WAITV(6); BAR();                     COMPUTE(7);
    WAITV(0); BAR();                     COMPUTE(8);

#undef LOADB
#undef STAGE1
#undef STAGE
#undef COMPUTE

    float biasv[2]; int oo[2];
    oo[0]=o0; oo[1]=o1;
    #pragma unroll
    for (int ot=0;ot<2;ot++)
        biasv[ot] = wb_l[oo[ot]] + gb_l[oo[ot]] + f0[(size_t)b*C_ + oo[ot]];
    unsigned short* AsF = &As4[0][0];   // reuse as [o][n] 128x72 for hT transpose
    if (apply_gelu) __syncthreads();    // all waves done reading buf0 (chunk 8)
    #pragma unroll
    for (int mt=0;mt<4;mt++){
        #pragma unroll
        for (int ot=0;ot<2;ot++){
            int nb = nb0 + mt*16 + quad*4;
            float v4[4];
            #pragma unroll
            for (int r=0;r<4;r++){
                float vv = acc[mt][ot][r] + biasv[ot];
                if (apply_gelu) vv = gelu_exact(vv);
                bool ok = (nb + r < N_);
                if (ok) hNo[(bN+nb+r)*C_ + oo[ot]] = f2bf(vv);
                v4[r] = ok ? vv : 0.f;   // pad rows -> exact zeros in hT
            }
            if (apply_gelu){
                uintx2 u; u.x = pack2(v4[0],v4[1]); u.y = pack2(v4[2],v4[3]);
                *(uintx2*)&AsF[oo[ot]*72 + mt*16 + quad*4] = u;
            }
        }
    }
    if (apply_gelu){
        __syncthreads();
        int orow = tid>>1, half = tid&1;
        uintx4 u0 = *(const uintx4*)&AsF[orow*72 + half*32];
        uintx4 u1 = *(const uintx4*)&AsF[orow*72 + half*32 + 8];
        unsigned short* dst = &hT[((size_t)b*C_ + orow)*NPAD + nb0 + half*32];
        *(uintx4*)dst       = u0;
        *(uintx4*)(dst + 8) = u1;
    }
}

// ---------------- head: MFMA fc1 + gelu + fc2 (counted-vmcnt staging) ----------

__global__ __launch_bounds__(256) void final_kernel(
    const unsigned short* __restrict__ hN, const unsigned short* __restrict__ fc1b16,
    const float* __restrict__ fc1b, const float* __restrict__ fc2w,
    const float* __restrict__ fc2b, float* __restrict__ out)
{
    __shared__ unsigned short Fs[2][4096];   // 2 bufs x (64 rows x 128 B)
    __shared__ float pp[4*64];
    int b = blockIdx.y;
    int nb0 = blockIdx.x*64;
    int tid = threadIdx.x;
    int wv = tid>>6, lane = tid&63, l15 = lane&15, quad = lane>>4;
    floatx4 acc[4][2];
    #pragma unroll
    for (int mt=0;mt<4;mt++){ acc[mt][0]=(floatx4){0,0,0,0}; acc[mt][1]=(floatx4){0,0,0,0}; }
    size_t bN = (size_t)b*N_;
    const unsigned short* sfp[2];
    #pragma unroll
    for (int q=0;q<2;q++){
        int li = q*256 + tid;
        int row = li>>3, u = (li&7) ^ (row&7);
        sfp[q] = hN + (bN + (size_t)(nb0 + row))*C_ + u*8;
    }
    int o0 = wv*32 + l15, o1 = o0 + 16;
    const unsigned short* w0p = fc1b16 + (size_t)o0*C_ + quad*8;
    const unsigned short* w1p = fc1b16 + (size_t)o1*C_ + quad*8;

#define FSTG(ch) do{ \
    _Pragma("unroll") \
    for (int q=0;q<2;q++) \
        __builtin_amdgcn_global_load_lds( \
            (const __attribute__((address_space(1))) void*)(sfp[q] + (ch)*64), \
            (__attribute__((address_space(3))) void*)&Fs[ch][q*2048 + wv*512], \
            16, 0, 0); }while(0)

#define FCOMP(ch) do{ \
    _Pragma("unroll") \
    for (int ks=0; ks<2; ks++){ \
        short8 bfr0 = *(const short8*)(w0p + (ch)*64 + ks*32); \
        short8 bfr1 = *(const short8*)(w1p + (ch)*64 + ks*32); \
        _Pragma("unroll") \
        for (int mt=0; mt<4; mt++){ \
            short8 af = *(const short8*)&Fs[ch][(mt*16+l15)*64 + (((ks*4+quad)^(l15&7))*8)]; \
            acc[mt][0] = __builtin_amdgcn_mfma_f32_16x16x32_bf16(af, bfr0, acc[mt][0], 0,0,0); \
            acc[mt][1] = __builtin_amdgcn_mfma_f32_16x16x32_bf16(af, bfr1, acc[mt][1], 0,0,0); \
        } } }while(0)

    FSTG(0); FSTG(1);
    WAITV(2); BAR(); FCOMP(0);
    WAITV(0); BAR(); FCOMP(1);
#undef FSTG
#undef FCOMP

    float fw0 = fc2w[o0], fw1 = fc2w[o1];
    float b0 = fc1b[o0], b1 = fc1b[o1];
    #pragma unroll
    for (int mt=0;mt<4;mt++){
        float s[4];
        #pragma unroll
        for (int r=0;r<4;r++)
            s[r] = fw0*gelu_exact(acc[mt][0][r] + b0) + fw1*gelu_exact(acc[mt][1][r] + b1);
        #pragma unroll
        for (int m=1;m<16;m<<=1)
            #pragma unroll
            for (int r=0;r<4;r++)
                s[r] += __shfl_xor(s[r], m, 16);
        if (l15 < 4){
            float v = (l15==0)?s[0]:(l15==1)?s[1]:(l15==2)?s[2]:s[3];
            pp[wv*64 + mt*16 + quad*4 + l15] = v;
        }
    }
    __syncthreads();
    if (tid < 64){
        float sum = pp[tid] + pp[64+tid] + pp[128+tid] + pp[192+tid] + fc2b[0];
        int n = nb0 + tid;
        if (n < N_) out[bN + n] = sum;
    }
}

// ---------------- launch ----------------

extern "C" void kernel_launch(void* const* d_in, const int* in_sizes, int n_in,
                              void* d_out, int out_size, void* d_ws, size_t ws_size,
                              hipStream_t stream)
{
    const float* x      = (const float*)d_in[0];
    const float* nodes  = (const float*)d_in[2];
    const float* nw     = (const float*)d_in[3];
    const int*   edges  = (const int*)  d_in[4];
    const float* egw    = (const float*)d_in[5];
    const float* modes  = (const float*)d_in[6];
    const float* latent = (const float*)d_in[7];
    const float* fc0w   = (const float*)d_in[8];
    const float* fc0b   = (const float*)d_in[9];
    const float* swc    = (const float*)d_in[10];
    const float* sws    = (const float*)d_in[11];
    const float* sw0    = (const float*)d_in[12];
    const float* ww     = (const float*)d_in[13];
    const float* wb     = (const float*)d_in[14];
    const float* gw     = (const float*)d_in[15];
    const float* gb     = (const float*)d_in[16];
    const float* fc1w   = (const float*)d_in[17];
    const float* fc1b   = (const float*)d_in[18];
    const float* fc2w   = (const float*)d_in[19];
    const float* fc2b   = (const float*)d_in[20];
    float* out = (float*)d_out;

    char* W = (char*)d_ws;
    size_t off = 0;
    unsigned short* bcB = (unsigned short*)(W+off); off += (size_t)NROWS*K_*2;
    unsigned short* bsB = (unsigned short*)(W+off); off += (size_t)NROWS*K_*2;
    unsigned short* wBt = (unsigned short*)(W+off); off += (size_t)B_*80*NPAD*2;
    unsigned short* hT  = (unsigned short*)(W+off); off += (size_t)B_*C_*NPAD*2;
    unsigned short* hNa = (unsigned short*)(W+off); off += (size_t)NROWS*C_*2;
    unsigned short* hNb = (unsigned short*)(W+off); off += (size_t)NROWS*C_*2;
    unsigned short* g   = (unsigned short*)(W+off); off += (size_t)NROWS*C_*3*2;
    unsigned short* wcat3=(unsigned short*)(W+off); off += (size_t)3*C_*512*2;
    unsigned short* wfb = (unsigned short*)(W+off); off += (size_t)B_*C_*64*2;
    unsigned short* fcw16=(unsigned short*)(W+off); off += (size_t)C_*C_*2;
    float* part = (float*)(W+off); off += (size_t)B_*64*80*C_*4;
    float* xq   = (float*)(W+off); off += (size_t)B_*80*C_*4;
    float* f0   = (float*)(W+off); off += (size_t)B_*C_*4;
    off = (off + 15) & ~(size_t)15;
    uintx4* epack = (uintx4*)(W+off); off += (size_t)B_*E_*16;
    int* cnt    = (int*)(W+off); off += (size_t)B_*N_*4;
    int* rowptr = (int*)(W+off); off += (size_t)B_*(N_+1)*4 + 16;
    int* cur    = (int*)(W+off); off += (size_t)B_*N_*4;

    (void)hipMemsetAsync(cnt, 0, (size_t)B_*N_*sizeof(int), stream);
    basis_kernel<<<dim3(NPAD/64, B_), 256, 0, stream>>>(
        nodes, nw, modes, latent, bcB, bsB, wBt);
    fc0_kernel  <<<(B_*NPAD+255)/256, 256, 0, stream>>>(x, fc0w, fc0b, hNa, hT);
    hist_kernel <<<(B_*E_+255)/256, 256, 0, stream>>>(edges, cnt);
    scan_kernel <<<B_, 1024, 0, stream>>>(cnt, rowptr, cur);
    fill_kernel <<<(B_*E_+255)/256, 256, 0, stream>>>(edges, egw, cur, epack);
    wconv_kernel<<<dim3(C_,4), 256, 0, stream>>>(ww, gw, fc1w, wcat3, fcw16);

    unsigned short* hc = hNa; unsigned short* hn = hNb;
    for (int l=0; l<3; ++l){
        stageA_kernel<<<dim3(128,B_), 256, 0, stream>>>(hT, wBt, part);
        reducePart_kernel<<<(B_*80*C_+255)/256, 256, 0, stream>>>(part, xq);
        mix_kernel<<<dim3(C_,B_), 64, 0, stream>>>(
            xq, swc + (size_t)l*C_*C_*K_, sws + (size_t)l*C_*C_*K_,
            sw0 + (size_t)l*C_*C_, wfb, f0);
        grad_kernel<<<N_, 256, 0, stream>>>(hc, epack, rowptr, g);
        gemm_kernel<<<dim3((N_+63)/64,B_), 256, 0, stream>>>(
            hc, g, bcB, bsB, wcat3 + (size_t)l*C_*512, wfb,
            wb + (size_t)l*C_, gb + (size_t)l*C_,
            f0, hn, hT, (l<2) ? 1 : 0);
        unsigned short* t = hc; hc = hn; hn = t;
    }
    final_kernel<<<dim3((N_+63)/64,B_), 256, 0, stream>>>(
        hc, fcw16, fc1b, fc2w, fc2b, out);
}